// Round 8
// baseline (171.561 us; speedup 1.0000x reference)
//
#include <hip/hip_runtime.h>
#include <stdint.h>

// ---------- types ----------
typedef __attribute__((ext_vector_type(8))) short s8v;   // 8 bf16 (4 VGPRs)
typedef __attribute__((ext_vector_type(4))) float f4v;   // MFMA accumulator

// ---------- helpers ----------
__device__ __forceinline__ unsigned short f2bf(float f) {
  unsigned u = __float_as_uint(f);
  u = u + 0x7FFFu + ((u >> 16) & 1u);   // RNE
  return (unsigned short)(u >> 16);
}
// monotone float->uint map: order(enc(a)) == order(a); 0 is below enc of any real float.
__device__ __forceinline__ unsigned encf(float f) {
  unsigned i = __float_as_uint(f);
  return (i & 0x80000000u) ? ~i : (i | 0x80000000u);
}
__device__ __forceinline__ float decf(unsigned u) {
  unsigned i = (u & 0x80000000u) ? (u & 0x7FFFFFFFu) : ~u;
  return __uint_as_float(i);
}
__device__ __forceinline__ void gload_lds16(const unsigned short* g, unsigned short* l) {
  __builtin_amdgcn_global_load_lds((const __attribute__((address_space(1))) void*)g,
                                   (__attribute__((address_space(3))) void*)l, 16, 0, 0);
}
__device__ __forceinline__ s8v u4s8(uint4 d) {
  union { uint4 u; s8v s; } x; x.u = d; return x.s;
}

// ---------- fused: q,a fp32->bf16; U -> Ut bf16 transposed; zero rmax/cmax + out ----------
__global__ void convert_kernel(const float4* __restrict__ q, const float4* __restrict__ a,
                               const float* __restrict__ U,
                               ushort4* __restrict__ qb, ushort4* __restrict__ ab,
                               unsigned short* __restrict__ Ut,
                               unsigned* __restrict__ rcmax, float* __restrict__ out) {
  const int bx = blockIdx.x;
  if (bx < 8192) {
    const int i = bx * 256 + threadIdx.x;
    float4 v = q[i];
    qb[i] = make_ushort4(f2bf(v.x), f2bf(v.y), f2bf(v.z), f2bf(v.w));
    float4 w = a[i];
    ab[i] = make_ushort4(f2bf(w.x), f2bf(w.y), f2bf(w.z), f2bf(w.w));
  } else if (bx < 8256) {
    // U transpose: 64 blocks x 256 thr, 4 elements each (tiny: 256 KB read)
    const int idx = (bx - 8192) * 256 + threadIdx.x;   // 0..16383
    const int n  = idx >> 6;
    const int k4 = (idx & 63) * 4;
    ushort4 o;
    o.x = f2bf(U[(k4 + 0) * 256 + n]);
    o.y = f2bf(U[(k4 + 1) * 256 + n]);
    o.z = f2bf(U[(k4 + 2) * 256 + n]);
    o.w = f2bf(U[(k4 + 3) * 256 + n]);
    *(ushort4*)&Ut[n * 256 + k4] = o;
  } else if (bx < 8320) {
    // zero rmax+cmax (64K uints): 64 blocks x 256 thr x 4
    const int idx = (bx - 8256) * 256 + threadIdx.x;   // 0..16383
    *(uint4*)&rcmax[idx * 4] = make_uint4(0u, 0u, 0u, 0u);
  } else {
    // zero out (8192 floats): 32 blocks (stream-ordered before wsum's atomics)
    out[(bx - 8320) * 256 + threadIdx.x] = 0.f;
  }
}

// ---------- fused qU-GEMM + S-max: one block per (batch, 128-row slab) ----------
// R21: fix of R20's AGPR corruption. R20 used hard-coded a0-a127 with CLOBBER
// lists — a clobber marks the regs dead after each asm, so between asm sites
// the allocator legally spilled its own VGPRs INTO them (LLVM AMDGPU spills
// VGPR->AGPR under pressure), corrupting the qU fragments (absmax 1.8e-3,
// nondeterministic 468 on replay). Fix: liveness-tracked "=a"/"a" constraints,
// NO clobbers — 128 dword fragments are SSA values the allocator must keep
// live (and in AGPRs) across the whole tile loop. Phase-1's compiler AGPR
// accumulators die at the epilogue (disjoint ranges); ~128 AGPR + ~100 arch
// <= 256 budget at 2 waves/EU.
// Structure (R19/R20): phase-2 wave grid 2x4 (64 qU-rows x 16 a-cols/wave),
// B-redundancy 2x (per-tile LDS reads 64 KB, was 128), depth-3 ring
// (4 x 32 KB SBUF), counted vmcnt(8), tiles 0/1 staged during phase-1 tail,
// phase-1 double-buffered. s_nop 1 covers VALU(accvgpr_read)->MFMA SrcA.
// Grid (b, tm): linear%8 == b%8 pins each batch to one XCD L2.
__global__ __attribute__((amdgpu_flat_work_group_size(512, 512), amdgpu_waves_per_eu(2, 2)))
void fused_qu_smax(const unsigned short* __restrict__ qb,
                   const unsigned short* __restrict__ Ut,
                   const unsigned short* __restrict__ ab,
                   unsigned* __restrict__ rowmax,
                   unsigned* __restrict__ colmax) {
  extern __shared__ char smem[];
  unsigned short* qUs    = (unsigned short*)smem;             // 64 KB: ph1 stage B image, then qU tile
  unsigned short* Bs2    = (unsigned short*)(smem + 65536);   // 64 KB: ph1 stage A image
  unsigned*       colLds = (unsigned*)(smem + 131072);        // 8 KB
  unsigned*       rowLds = (unsigned*)(smem + 139264);        // 512 B
#define SBUF(k) ((unsigned short*)(smem + ((k) << 15)))       // 4 x 32 KB ring (phase 2)

  const int tid = threadIdx.x;
  const int b = blockIdx.x, tm = blockIdx.y;

  const int lane = tid & 63;
  const int m16  = lane & 15;
  const int quad = lane >> 4;
  const int wave = tid >> 6;          // 0..7
  const int wm   = wave >> 2;         // 0..1: ph1 row half / ph2 64-row group
  const int wn   = wave & 3;          // 0..3: ph1 col group / ph2 16-col group
  const int wc16 = wn * 16;           // phase 2: 16-col group base
  const int srow = tid >> 3;          // staging row (64/issue)
  const int scol = (((tid & 7) ^ (srow & 7))) * 8;   // swizzled source chunk

  #pragma unroll
  for (int i = 0; i < 4; ++i) colLds[i * 512 + tid] = 0u;
  if (tid < 128) rowLds[tid] = 0u;

  const unsigned short* Ab_ = ab + (long)b * 2048 * 256;

  // phase-2 a-tile stage: 64 rows x 256 cols bf16 = 32 KB, 4 issues/thread
#define STG64(tb, dst) do {                                                    \
    _Pragma("unroll")                                                          \
    for (int e_ = 0; e_ < 4; ++e_) {                                           \
      const int u_ = e_ * 512 + tid;        /* 16B unit: row=u>>5, chunk=u&31 */ \
      const int row_ = u_ >> 5;                                                \
      const int chs_ = (u_ & 31) ^ (row_ & 7);                                 \
      gload_lds16(Ab_ + (long)((tb) * 64 + row_) * 256 + chs_ * 8,             \
                  &(dst)[u_ * 8]);                                             \
    }                                                                          \
  } while (0)

  // ================= phase 1: qU tile -> LDS (double-buffered) =================
  const unsigned short* Aq = qb + ((long)b * 2048 + tm * 128) * 256;
  {
    f4v acc[4][4] = {};

#define STAGE1(kt, dst) do {                                                   \
    const int k0_ = (kt) * 64;                                                 \
    _Pragma("unroll")                                                          \
    for (int i_ = 0; i_ < 2; ++i_)                                             \
      gload_lds16(Aq + (long)(i_ * 64 + srow) * 256 + k0_ + scol,              \
                  &(dst)[i_ * 4096 + tid * 8]);                                \
    _Pragma("unroll")                                                          \
    for (int i_ = 0; i_ < 4; ++i_)                                             \
      gload_lds16(Ut + (long)(i_ * 64 + srow) * 256 + k0_ + scol,              \
                  &(dst)[8192 + i_ * 4096 + tid * 8]);                         \
  } while (0)

#define COMPUTE1(buf) do {                                                     \
    _Pragma("unroll")                                                          \
    for (int kk_ = 0; kk_ < 2; ++kk_) {                                        \
      const int cs_ = ((kk_ * 4 + quad) ^ (m16 & 7)) * 8;                      \
      s8v af_[4], bf_[4];                                                      \
      _Pragma("unroll")                                                        \
      for (int i_ = 0; i_ < 4; ++i_)                                           \
        af_[i_] = *(const s8v*)&(buf)[(wm * 64 + i_ * 16 + m16) * 64 + cs_];   \
      _Pragma("unroll")                                                        \
      for (int j_ = 0; j_ < 4; ++j_)                                           \
        bf_[j_] = *(const s8v*)&(buf)[8192 + (wn * 64 + j_ * 16 + m16) * 64 + cs_]; \
      _Pragma("unroll")                                                        \
      for (int i_ = 0; i_ < 4; ++i_)                                           \
        _Pragma("unroll")                                                      \
        for (int j_ = 0; j_ < 4; ++j_)                                         \
          acc[i_][j_] = __builtin_amdgcn_mfma_f32_16x16x32_bf16(af_[i_], bf_[j_], acc[i_][j_], 0, 0, 0); \
    }                                                                          \
  } while (0)

    STAGE1(0, Bs2);
    STAGE1(1, qUs);
    asm volatile("s_waitcnt vmcnt(6)" ::: "memory");   // kt0 landed
    __builtin_amdgcn_s_barrier();
    COMPUTE1(Bs2);
    __builtin_amdgcn_s_barrier();                      // Bs2 reads done -> restage-safe
    STAGE1(2, Bs2);
    asm volatile("s_waitcnt vmcnt(6)" ::: "memory");   // kt1 landed
    __builtin_amdgcn_s_barrier();
    COMPUTE1(qUs);
    __builtin_amdgcn_s_barrier();                      // qUs reads done -> restage-safe
    STAGE1(3, qUs);
    asm volatile("s_waitcnt vmcnt(6)" ::: "memory");   // kt2 landed
    __builtin_amdgcn_s_barrier();
    COMPUTE1(Bs2);                                     // kt2
    asm volatile("s_waitcnt vmcnt(0)" ::: "memory");   // kt3 data fully landed
    __builtin_amdgcn_s_barrier();                      // also: Bs2 image free
    // early a-tile stages into S2/S3 (inside old Bs2 image) — fly under
    // kt3 compute + epilogue + AGPR init
    STG64(0, SBUF(2));
    STG64(1, SBUF(3));
    COMPUTE1(qUs);                                     // kt3
    asm volatile("s_waitcnt lgkmcnt(0)" ::: "memory"); // kt3 LDS reads returned
    __builtin_amdgcn_s_barrier();                      // (no vmcnt drain!)

    // write acc -> qUs (row-major 256 cols, swizzled 16B chunks)
    // C/D layout: col = lane&15, row = quad*4 + reg (verified mapping)
    #pragma unroll
    for (int i = 0; i < 4; ++i)
      #pragma unroll
      for (int r = 0; r < 4; ++r) {
        const int lr = wm * 64 + i * 16 + quad * 4 + r;
        #pragma unroll
        for (int j = 0; j < 4; ++j) {
          const int col = wn * 64 + j * 16 + m16;
          const int ch = (col >> 3) ^ (lr & 7);
          qUs[lr * 256 + ch * 8 + (col & 7)] = f2bf(acc[i][j][r]);
        }
      }
  }
  asm volatile("s_waitcnt lgkmcnt(0)" ::: "memory");   // epilogue writes visible
  __builtin_amdgcn_s_barrier();                        // (no vmcnt drain!)

  // ============ phase 2: 32 a-tiles (64 rows) vs AGPR-resident qU ============
  // 128 liveness-tracked AGPR dwords: aqr[i][kq][0..3] = fragment (rows
  // wm*64+i*16.., K-slice kq). "=a" defs / "a" uses, NO clobbers — the
  // allocator keeps them live in AGPRs for the whole loop.
  unsigned aqr[4][8][4];

#define AQW(I, KQ) do {                                                        \
    uint4 t_ = *(const uint4*)&qUs[(wm * 64 + (I) * 16 + m16) * 256 +          \
                                   (((KQ) * 4 + quad) ^ (m16 & 7)) * 8];       \
    asm volatile("v_accvgpr_write_b32 %0, %4\n\t"                              \
                 "v_accvgpr_write_b32 %1, %5\n\t"                              \
                 "v_accvgpr_write_b32 %2, %6\n\t"                              \
                 "v_accvgpr_write_b32 %3, %7"                                  \
                 : "=a"(aqr[I][KQ][0]), "=a"(aqr[I][KQ][1]),                   \
                   "=a"(aqr[I][KQ][2]), "=a"(aqr[I][KQ][3])                    \
                 : "v"(t_.x), "v"(t_.y), "v"(t_.z), "v"(t_.w));                \
  } while (0)

#define AQR(I, KQ, D)                                                          \
    asm volatile("v_accvgpr_read_b32 %0, %4\n\t"                               \
                 "v_accvgpr_read_b32 %1, %5\n\t"                               \
                 "v_accvgpr_read_b32 %2, %6\n\t"                               \
                 "v_accvgpr_read_b32 %3, %7\n\t"                               \
                 "s_nop 1"                                                     \
                 : "=v"((D).x), "=v"((D).y), "=v"((D).z), "=v"((D).w)          \
                 : "a"(aqr[I][KQ][0]), "a"(aqr[I][KQ][1]),                     \
                   "a"(aqr[I][KQ][2]), "a"(aqr[I][KQ][3]))

#define MF(D, BV, C) __builtin_amdgcn_mfma_f32_16x16x32_bf16(u4s8(D), (BV), (C), 0, 0, 0)

  AQW(0, 0); AQW(0, 1); AQW(0, 2); AQW(0, 3);
  AQW(0, 4); AQW(0, 5); AQW(0, 6); AQW(0, 7);
  AQW(1, 0); AQW(1, 1); AQW(1, 2); AQW(1, 3);
  AQW(1, 4); AQW(1, 5); AQW(1, 6); AQW(1, 7);
  AQW(2, 0); AQW(2, 1); AQW(2, 2); AQW(2, 3);
  AQW(2, 4); AQW(2, 5); AQW(2, 6); AQW(2, 7);
  AQW(3, 0); AQW(3, 1); AQW(3, 2); AQW(3, 3);
  AQW(3, 4); AQW(3, 5); AQW(3, 6); AQW(3, 7);
  // all waves' qU reads DATA-RETURNED before the S0/S1 region is restaged
  asm volatile("s_waitcnt lgkmcnt(0)" ::: "memory");
  __builtin_amdgcn_s_barrier();
  STG64(2, SBUF(0));                                   // qU tile region now dead

  float rmx[4][4];
  #pragma unroll
  for (int i = 0; i < 4; ++i)
    #pragma unroll
    for (int r = 0; r < 4; ++r) rmx[i][r] = -3.4e38f;

  // per tile: 8 ds_read_b128 (B only; A comes from AGPRs), 32 MFMA.
#define CMP64(tb, buf) do {                                                    \
    f4v c0 = {}, c1 = {}, c2 = {}, c3 = {};                                    \
    const unsigned short* bp_ = &(buf)[(wc16 + m16) * 256];                    \
    const s8v bv0 = *(const s8v*)&bp_[((0 * 4 + quad) ^ (m16 & 7)) * 8];       \
    const s8v bv1 = *(const s8v*)&bp_[((1 * 4 + quad) ^ (m16 & 7)) * 8];       \
    const s8v bv2 = *(const s8v*)&bp_[((2 * 4 + quad) ^ (m16 & 7)) * 8];       \
    const s8v bv3 = *(const s8v*)&bp_[((3 * 4 + quad) ^ (m16 & 7)) * 8];       \
    const s8v bv4 = *(const s8v*)&bp_[((4 * 4 + quad) ^ (m16 & 7)) * 8];       \
    const s8v bv5 = *(const s8v*)&bp_[((5 * 4 + quad) ^ (m16 & 7)) * 8];       \
    const s8v bv6 = *(const s8v*)&bp_[((6 * 4 + quad) ^ (m16 & 7)) * 8];       \
    const s8v bv7 = *(const s8v*)&bp_[((7 * 4 + quad) ^ (m16 & 7)) * 8];       \
    { uint4 d_; AQR(0, 0, d_); c0 = MF(d_, bv0, c0); }                         \
    { uint4 d_; AQR(1, 0, d_); c1 = MF(d_, bv0, c1); }                         \
    { uint4 d_; AQR(2, 0, d_); c2 = MF(d_, bv0, c2); }                         \
    { uint4 d_; AQR(3, 0, d_); c3 = MF(d_, bv0, c3); }                         \
    { uint4 d_; AQR(0, 1, d_); c0 = MF(d_, bv1, c0); }                         \
    { uint4 d_; AQR(1, 1, d_); c1 = MF(d_, bv1, c1); }                         \
    { uint4 d_; AQR(2, 1, d_); c2 = MF(d_, bv1, c2); }                         \
    { uint4 d_; AQR(3, 1, d_); c3 = MF(d_, bv1, c3); }                         \
    { uint4 d_; AQR(0, 2, d_); c0 = MF(d_, bv2, c0); }                         \
    { uint4 d_; AQR(1, 2, d_); c1 = MF(d_, bv2, c1); }                         \
    { uint4 d_; AQR(2, 2, d_); c2 = MF(d_, bv2, c2); }                         \
    { uint4 d_; AQR(3, 2, d_); c3 = MF(d_, bv2, c3); }                         \
    { uint4 d_; AQR(0, 3, d_); c0 = MF(d_, bv3, c0); }                         \
    { uint4 d_; AQR(1, 3, d_); c1 = MF(d_, bv3, c1); }                         \
    { uint4 d_; AQR(2, 3, d_); c2 = MF(d_, bv3, c2); }                         \
    { uint4 d_; AQR(3, 3, d_); c3 = MF(d_, bv3, c3); }                         \
    { uint4 d_; AQR(0, 4, d_); c0 = MF(d_, bv4, c0); }                         \
    { uint4 d_; AQR(1, 4, d_); c1 = MF(d_, bv4, c1); }                         \
    { uint4 d_; AQR(2, 4, d_); c2 = MF(d_, bv4, c2); }                         \
    { uint4 d_; AQR(3, 4, d_); c3 = MF(d_, bv4, c3); }                         \
    { uint4 d_; AQR(0, 5, d_); c0 = MF(d_, bv5, c0); }                         \
    { uint4 d_; AQR(1, 5, d_); c1 = MF(d_, bv5, c1); }                         \
    { uint4 d_; AQR(2, 5, d_); c2 = MF(d_, bv5, c2); }                         \
    { uint4 d_; AQR(3, 5, d_); c3 = MF(d_, bv5, c3); }                         \
    { uint4 d_; AQR(0, 6, d_); c0 = MF(d_, bv6, c0); }                         \
    { uint4 d_; AQR(1, 6, d_); c1 = MF(d_, bv6, c1); }                         \
    { uint4 d_; AQR(2, 6, d_); c2 = MF(d_, bv6, c2); }                         \
    { uint4 d_; AQR(3, 6, d_); c3 = MF(d_, bv6, c3); }                         \
    { uint4 d_; AQR(0, 7, d_); c0 = MF(d_, bv7, c0); }                         \
    { uint4 d_; AQR(1, 7, d_); c1 = MF(d_, bv7, c1); }                         \
    { uint4 d_; AQR(2, 7, d_); c2 = MF(d_, bv7, c2); }                         \
    { uint4 d_; AQR(3, 7, d_); c3 = MF(d_, bv7, c3); }                         \
    _Pragma("unroll")                                                          \
    for (int r_ = 0; r_ < 4; ++r_) {                                           \
      rmx[0][r_] = fmaxf(rmx[0][r_], c0[r_]);                                  \
      rmx[1][r_] = fmaxf(rmx[1][r_], c1[r_]);                                  \
      rmx[2][r_] = fmaxf(rmx[2][r_], c2[r_]);                                  \
      rmx[3][r_] = fmaxf(rmx[3][r_], c3[r_]);                                  \
    }                                                                          \
    float v_ = fmaxf(fmaxf(fmaxf(c0[0], c0[1]), fmaxf(c0[2], c0[3])),          \
                     fmaxf(fmaxf(c1[0], c1[1]), fmaxf(c1[2], c1[3])));         \
    v_ = fmaxf(v_, fmaxf(fmaxf(fmaxf(c2[0], c2[1]), fmaxf(c2[2], c2[3])),      \
                         fmaxf(fmaxf(c3[0], c3[1]), fmaxf(c3[2], c3[3]))));    \
    v_ = fmaxf(v_, __shfl_xor(v_, 16));                                        \
    v_ = fmaxf(v_, __shfl_xor(v_, 32));                                        \
    if (quad == 0) atomicMax(&colLds[(tb) * 64 + wc16 + m16], encf(v_));       \
  } while (0)

  // depth-3 ring pipeline: before compute(t), tiles t+1..t+3 staged (12 in
  // flight) -> vmcnt(8) proves tile t landed. stage(t+3) targets SBUF((t+1)&3)
  // = the buffer freed by compute(t-1); two barriers separate them.
  #pragma unroll 1
  for (int t = 0; t < 30; ++t) {
    asm volatile("s_waitcnt vmcnt(8)" ::: "memory");   // tile t's 4/thread landed
    __builtin_amdgcn_s_barrier();                      // ...for ALL waves
    if (t <= 28) STG64(t + 3, SBUF((t + 1) & 3));
    CMP64(t, SBUF((t + 2) & 3));
    __builtin_amdgcn_s_barrier();                      // buf reads done -> restage-safe
  }
  asm volatile("s_waitcnt vmcnt(4)" ::: "memory");     // tile 30 landed
  __builtin_amdgcn_s_barrier();
  CMP64(30, SBUF(0));
  __builtin_amdgcn_s_barrier();
  asm volatile("s_waitcnt vmcnt(0)" ::: "memory");     // tile 31 landed
  __builtin_amdgcn_s_barrier();
  CMP64(31, SBUF(1));

  // ---- final row maxes: shuffle over m16, combine via LDS, store ----
  #pragma unroll
  for (int i = 0; i < 4; ++i)
    #pragma unroll
    for (int r = 0; r < 4; ++r) {
      float v = rmx[i][r];
      #pragma unroll
      for (int d2 = 1; d2 < 16; d2 <<= 1) v = fmaxf(v, __shfl_xor(v, d2));
      if (m16 == 0) atomicMax(&rowLds[wm * 64 + i * 16 + quad * 4 + r], encf(v));
    }
  __syncthreads();
  if (tid < 128)
    rowmax[(long)b * 2048 + tm * 128 + tid] = rowLds[tid];   // plain store (block owns rows)
  // ---- col maxes: one global atomic pass ----
  #pragma unroll
  for (int i = 0; i < 4; ++i)
    atomicMax(&colmax[(long)b * 2048 + i * 512 + tid], colLds[i * 512 + tid]);
}

// ---------- fused softmax + weighted sum (bf16 inputs, 16B/lane loads) ----------
__global__ void wsum_kernel(const uint4* __restrict__ qb, const uint4* __restrict__ ab,
                            const unsigned* __restrict__ rowmax, const unsigned* __restrict__ colmax,
                            float* __restrict__ out) {
  const int tid = threadIdx.x;
  const int chunk = blockIdx.x;
  const int b = blockIdx.y;
  const int z = blockIdx.z;
  const unsigned* e = z ? colmax : rowmax;
  const uint4* src = z ? ab : qb;

  __shared__ float sm[4];
  __shared__ float ss[4];
  __shared__ float wLds[128];
  __shared__ float red[256 * 8];   // 8 KB

  float x[8];
  float m = -3.4e38f;
  #pragma unroll
  for (int j = 0; j < 8; ++j) {
    x[j] = tanhf(decf(e[b * 2048 + j * 256 + tid]));
    m = fmaxf(m, x[j]);
  }
  #pragma unroll
  for (int d2 = 1; d2 < 64; d2 <<= 1) m = fmaxf(m, __shfl_xor(m, d2));
  if ((tid & 63) == 0) sm[tid >> 6] = m;
  __syncthreads();
  m = fmaxf(fmaxf(sm[0], sm[1]), fmaxf(sm[2], sm[3]));
  float s = 0.f;
  #pragma unroll
  for (int j = 0; j < 8; ++j) s += expf(x[j] - m);
  #pragma unroll
  for (int d2 = 1; d2 < 64; d2 <<= 1) s += __shfl_xor(s, d2);
  if ((tid & 63) == 0) ss[tid >> 6] = s;
  __syncthreads();
  const float inv = 1.f / (ss[0] + ss[1] + ss[2] + ss[3]);

  if (tid < 128) {
    float xv = tanhf(decf(e[b * 2048 + chunk * 128 + tid]));
    wLds[tid] = expf(xv - m) * inv;
  }
  __syncthreads();

  const int dg = tid & 31;
  const int rg = tid >> 5;       // 0..7, rows stride 8
  float acc[8] = {};
  const long rowbase = (long)b * 2048 + chunk * 128;
  for (int t = rg; t < 128; t += 8) {
    const float wgt = wLds[t];
    uint4 v = src[(rowbase + t) * 32 + dg];
    acc[0] += wgt * __uint_as_float(v.x << 16);
    acc[1] += wgt * __uint_as_float(v.x & 0xFFFF0000u);
    acc[2] += wgt * __uint_as_float(v.y << 16);
    acc[3] += wgt * __uint_as_float(v.y & 0xFFFF0000u);
    acc[4] += wgt * __uint_as_float(v.z << 16);
    acc[5] += wgt * __uint_as_float(v.z & 0xFFFF0000u);
    acc[6] += wgt * __uint_as_float(v.w << 16);
    acc[7] += wgt * __uint_as_float(v.w & 0xFFFF0000u);
  }
  #pragma unroll
  for (int k = 0; k < 8; ++k) red[tid * 8 + k] = acc[k];
  __syncthreads();
  if (tid < 32) {
    #pragma unroll
    for (int k = 0; k < 8; ++k) {
      float v = 0.f;
      #pragma unroll
      for (int g = 0; g < 8; ++g) v += red[((g << 5) | tid) * 8 + k];
      atomicAdd(&out[z * 4096 + b * 256 + tid * 8 + k], v);
    }
  }
}

// ---------- launch ----------
extern "C" void kernel_launch(void* const* d_in, const int* in_sizes, int n_in,
                              void* d_out, int out_size, void* d_ws, size_t ws_size,
                              hipStream_t stream) {
  const float* q = (const float*)d_in[0];
  const float* a = (const float*)d_in[1];
  const float* U = (const float*)d_in[2];
  float* out = (float*)d_out;

  char* w = (char*)d_ws;
  unsigned short* qb = (unsigned short*)w;                       // 16 MB
  unsigned short* ab = (unsigned short*)(w + (16ull << 20));     // 16 MB
  unsigned short* Ut = (unsigned short*)(w + (32ull << 20));     // 128 KB
  unsigned* rmax = (unsigned*)(w + (32ull << 20) + (128ull << 10));
  unsigned* cmax = rmax + 32768;

  // allow 139776 B dynamic LDS for the fused kernel (host-side, idempotent)
  constexpr int SMEM = 139776;
  hipFuncSetAttribute((const void*)fused_qu_smax,
                      hipFuncAttributeMaxDynamicSharedMemorySize, SMEM);

  // fused q/a bf16-cast + U transpose + rmax/cmax zero + out zero
  convert_kernel<<<8352, 256, 0, stream>>>((const float4*)q, (const float4*)a, U,
                                           (ushort4*)qb, (ushort4*)ab, Ut, rmax, out);

  // qU tile in LDS + S row/col maxes; grid (b, tm) -> XCD == b%8; 8 waves/block
  fused_qu_smax<<<dim3(16, 16), 512, SMEM, stream>>>(qb, Ut, ab, rmax, cmax);

  // fused softmax + weighted pooling (bf16, 16B/lane)
  wsum_kernel<<<dim3(16, 16, 2), 256, 0, stream>>>((const uint4*)qb, (const uint4*)ab,
                                                   rmax, cmax, out);
}

// Round 9
// 156.605 us; speedup vs baseline: 1.0955x; 1.0955x over previous
//
#include <hip/hip_runtime.h>
#include <stdint.h>

// ---------- types ----------
typedef __attribute__((ext_vector_type(8))) short s8v;   // 8 bf16 (4 VGPRs)
typedef __attribute__((ext_vector_type(4))) float f4v;   // MFMA accumulator
typedef __attribute__((ext_vector_type(4))) unsigned u4v; // 128-bit fragment

// ---------- helpers ----------
__device__ __forceinline__ unsigned short f2bf(float f) {
  unsigned u = __float_as_uint(f);
  u = u + 0x7FFFu + ((u >> 16) & 1u);   // RNE
  return (unsigned short)(u >> 16);
}
// monotone float->uint map: order(enc(a)) == order(a); 0 is below enc of any real float.
__device__ __forceinline__ unsigned encf(float f) {
  unsigned i = __float_as_uint(f);
  return (i & 0x80000000u) ? ~i : (i | 0x80000000u);
}
__device__ __forceinline__ float decf(unsigned u) {
  unsigned i = (u & 0x80000000u) ? (u & 0x7FFFFFFFu) : ~u;
  return __uint_as_float(i);
}
__device__ __forceinline__ void gload_lds16(const unsigned short* g, unsigned short* l) {
  __builtin_amdgcn_global_load_lds((const __attribute__((address_space(1))) void*)g,
                                   (__attribute__((address_space(3))) void*)l, 16, 0, 0);
}

// ---------- fused: q,a fp32->bf16; U -> Ut bf16 transposed; zero rmax/cmax + out ----------
__global__ void convert_kernel(const float4* __restrict__ q, const float4* __restrict__ a,
                               const float* __restrict__ U,
                               ushort4* __restrict__ qb, ushort4* __restrict__ ab,
                               unsigned short* __restrict__ Ut,
                               unsigned* __restrict__ rcmax, float* __restrict__ out) {
  const int bx = blockIdx.x;
  if (bx < 8192) {
    const int i = bx * 256 + threadIdx.x;
    float4 v = q[i];
    qb[i] = make_ushort4(f2bf(v.x), f2bf(v.y), f2bf(v.z), f2bf(v.w));
    float4 w = a[i];
    ab[i] = make_ushort4(f2bf(w.x), f2bf(w.y), f2bf(w.z), f2bf(w.w));
  } else if (bx < 8256) {
    // U transpose: 64 blocks x 256 thr, 4 elements each (tiny: 256 KB read)
    const int idx = (bx - 8192) * 256 + threadIdx.x;   // 0..16383
    const int n  = idx >> 6;
    const int k4 = (idx & 63) * 4;
    ushort4 o;
    o.x = f2bf(U[(k4 + 0) * 256 + n]);
    o.y = f2bf(U[(k4 + 1) * 256 + n]);
    o.z = f2bf(U[(k4 + 2) * 256 + n]);
    o.w = f2bf(U[(k4 + 3) * 256 + n]);
    *(ushort4*)&Ut[n * 256 + k4] = o;
  } else if (bx < 8320) {
    // zero rmax+cmax (64K uints): 64 blocks x 256 thr x 4
    const int idx = (bx - 8256) * 256 + threadIdx.x;   // 0..16383
    *(uint4*)&rcmax[idx * 4] = make_uint4(0u, 0u, 0u, 0u);
  } else {
    // zero out (8192 floats): 32 blocks (stream-ordered before wsum's atomics)
    out[(bx - 8320) * 256 + threadIdx.x] = 0.f;
  }
}

// ---------- fused qU-GEMM + S-max: one block per (batch, 128-row slab) ----------
// R22: delete R21's AGPR->VGPR transport. R21 proved AGPR residency correct
// (liveness-tracked "=a"/"a"; conflicts halved 4.33M->2.36M as predicted) but
// paid 128 v_accvgpr_read + 32 s_nop per tile in order-pinned volatile asm:
// VALUBusy 27->51%, fused 51.5->67.5us. Per ISA §10 MFMA SrcA can BE an AGPR —
// so the MFMA is now inline asm with "a" SrcA:
//    v_mfma_f32_16x16x32_bf16 %0, %1, %2, %0  ("+v" acc, "a" frag, "v" B)
// aqf[4][8] are plain LDS loads whose only uses are "a" inputs -> allocator
// keeps them in AGPRs (liveness-tracked, no R20-style clobber corruption).
// Asm is non-volatile (pure; data deps order it) so MFMAs interleave with
// ds_reads. Hazard we own (asm opaque to hazard recognizer): MFMA-write(c) ->
// VALU-read in reductions, covered by 2x s_nop 7 after the MFMA block; c0 read
// first. MFMA->MFMA same-acc is HW-interlocked; AGPR writes are once, far away.
// Structure (R19/R21): phase-2 wave grid 2x4 (64 qU-rows x 16 a-cols/wave),
// B-redundancy 2x (8 ds_read_b128/tile/wave), depth-3 ring (4 x 32 KB SBUF),
// counted vmcnt(8), tiles 0/1 staged during phase-1 tail, ph1 double-buffered.
// Grid (b, tm): linear%8 == b%8 pins each batch to one XCD L2.
__global__ __attribute__((amdgpu_flat_work_group_size(512, 512), amdgpu_waves_per_eu(2, 2)))
void fused_qu_smax(const unsigned short* __restrict__ qb,
                   const unsigned short* __restrict__ Ut,
                   const unsigned short* __restrict__ ab,
                   unsigned* __restrict__ rowmax,
                   unsigned* __restrict__ colmax) {
  extern __shared__ char smem[];
  unsigned short* qUs    = (unsigned short*)smem;             // 64 KB: ph1 stage B image, then qU tile
  unsigned short* Bs2    = (unsigned short*)(smem + 65536);   // 64 KB: ph1 stage A image
  unsigned*       colLds = (unsigned*)(smem + 131072);        // 8 KB
  unsigned*       rowLds = (unsigned*)(smem + 139264);        // 512 B
#define SBUF(k) ((unsigned short*)(smem + ((k) << 15)))       // 4 x 32 KB ring (phase 2)

  const int tid = threadIdx.x;
  const int b = blockIdx.x, tm = blockIdx.y;

  const int lane = tid & 63;
  const int m16  = lane & 15;
  const int quad = lane >> 4;
  const int wave = tid >> 6;          // 0..7
  const int wm   = wave >> 2;         // 0..1: ph1 row half / ph2 64-row group
  const int wn   = wave & 3;          // 0..3: ph1 col group / ph2 16-col group
  const int wc16 = wn * 16;           // phase 2: 16-col group base
  const int srow = tid >> 3;          // staging row (64/issue)
  const int scol = (((tid & 7) ^ (srow & 7))) * 8;   // swizzled source chunk

  #pragma unroll
  for (int i = 0; i < 4; ++i) colLds[i * 512 + tid] = 0u;
  if (tid < 128) rowLds[tid] = 0u;

  const unsigned short* Ab_ = ab + (long)b * 2048 * 256;

  // phase-2 a-tile stage: 64 rows x 256 cols bf16 = 32 KB, 4 issues/thread
#define STG64(tb, dst) do {                                                    \
    _Pragma("unroll")                                                          \
    for (int e_ = 0; e_ < 4; ++e_) {                                           \
      const int u_ = e_ * 512 + tid;        /* 16B unit: row=u>>5, chunk=u&31 */ \
      const int row_ = u_ >> 5;                                                \
      const int chs_ = (u_ & 31) ^ (row_ & 7);                                 \
      gload_lds16(Ab_ + (long)((tb) * 64 + row_) * 256 + chs_ * 8,             \
                  &(dst)[u_ * 8]);                                             \
    }                                                                          \
  } while (0)

  // ================= phase 1: qU tile -> LDS (double-buffered) =================
  const unsigned short* Aq = qb + ((long)b * 2048 + tm * 128) * 256;
  {
    f4v acc[4][4] = {};

#define STAGE1(kt, dst) do {                                                   \
    const int k0_ = (kt) * 64;                                                 \
    _Pragma("unroll")                                                          \
    for (int i_ = 0; i_ < 2; ++i_)                                             \
      gload_lds16(Aq + (long)(i_ * 64 + srow) * 256 + k0_ + scol,              \
                  &(dst)[i_ * 4096 + tid * 8]);                                \
    _Pragma("unroll")                                                          \
    for (int i_ = 0; i_ < 4; ++i_)                                             \
      gload_lds16(Ut + (long)(i_ * 64 + srow) * 256 + k0_ + scol,              \
                  &(dst)[8192 + i_ * 4096 + tid * 8]);                         \
  } while (0)

#define COMPUTE1(buf) do {                                                     \
    _Pragma("unroll")                                                          \
    for (int kk_ = 0; kk_ < 2; ++kk_) {                                        \
      const int cs_ = ((kk_ * 4 + quad) ^ (m16 & 7)) * 8;                      \
      s8v af_[4], bf_[4];                                                      \
      _Pragma("unroll")                                                        \
      for (int i_ = 0; i_ < 4; ++i_)                                           \
        af_[i_] = *(const s8v*)&(buf)[(wm * 64 + i_ * 16 + m16) * 64 + cs_];   \
      _Pragma("unroll")                                                        \
      for (int j_ = 0; j_ < 4; ++j_)                                           \
        bf_[j_] = *(const s8v*)&(buf)[8192 + (wn * 64 + j_ * 16 + m16) * 64 + cs_]; \
      _Pragma("unroll")                                                        \
      for (int i_ = 0; i_ < 4; ++i_)                                           \
        _Pragma("unroll")                                                      \
        for (int j_ = 0; j_ < 4; ++j_)                                         \
          acc[i_][j_] = __builtin_amdgcn_mfma_f32_16x16x32_bf16(af_[i_], bf_[j_], acc[i_][j_], 0, 0, 0); \
    }                                                                          \
  } while (0)

    STAGE1(0, Bs2);
    STAGE1(1, qUs);
    asm volatile("s_waitcnt vmcnt(6)" ::: "memory");   // kt0 landed
    __builtin_amdgcn_s_barrier();
    COMPUTE1(Bs2);
    __builtin_amdgcn_s_barrier();                      // Bs2 reads done -> restage-safe
    STAGE1(2, Bs2);
    asm volatile("s_waitcnt vmcnt(6)" ::: "memory");   // kt1 landed
    __builtin_amdgcn_s_barrier();
    COMPUTE1(qUs);
    __builtin_amdgcn_s_barrier();                      // qUs reads done -> restage-safe
    STAGE1(3, qUs);
    asm volatile("s_waitcnt vmcnt(6)" ::: "memory");   // kt2 landed
    __builtin_amdgcn_s_barrier();
    COMPUTE1(Bs2);                                     // kt2
    asm volatile("s_waitcnt vmcnt(0)" ::: "memory");   // kt3 data fully landed
    __builtin_amdgcn_s_barrier();                      // also: Bs2 image free
    // early a-tile stages into S2/S3 (inside old Bs2 image) — fly under
    // kt3 compute + epilogue + fragment init
    STG64(0, SBUF(2));
    STG64(1, SBUF(3));
    COMPUTE1(qUs);                                     // kt3
    asm volatile("s_waitcnt lgkmcnt(0)" ::: "memory"); // kt3 LDS reads returned
    __builtin_amdgcn_s_barrier();                      // (no vmcnt drain!)

    // write acc -> qUs (row-major 256 cols, swizzled 16B chunks)
    // C/D layout: col = lane&15, row = quad*4 + reg (verified mapping)
    #pragma unroll
    for (int i = 0; i < 4; ++i)
      #pragma unroll
      for (int r = 0; r < 4; ++r) {
        const int lr = wm * 64 + i * 16 + quad * 4 + r;
        #pragma unroll
        for (int j = 0; j < 4; ++j) {
          const int col = wn * 64 + j * 16 + m16;
          const int ch = (col >> 3) ^ (lr & 7);
          qUs[lr * 256 + ch * 8 + (col & 7)] = f2bf(acc[i][j][r]);
        }
      }
  }
  asm volatile("s_waitcnt lgkmcnt(0)" ::: "memory");   // epilogue writes visible
  __builtin_amdgcn_s_barrier();                        // (no vmcnt drain!)

  // ============ phase 2: 32 a-tiles (64 rows) vs AGPR-resident qU ============
  // aqf[i][kq] = qU fragment (rows wm*64+i*16.., K-slice kq), 128 dwords total.
  // Plain LDS loads; every use is an "a" asm input -> lives in AGPRs.
  u4v aqf[4][8];
  #pragma unroll
  for (int i = 0; i < 4; ++i)
    #pragma unroll
    for (int kq = 0; kq < 8; ++kq)
      aqf[i][kq] = *(const u4v*)&qUs[(wm * 64 + i * 16 + m16) * 256 +
                                     ((kq * 4 + quad) ^ (m16 & 7)) * 8];
  // all waves' qU reads DATA-RETURNED before the S0/S1 region is restaged
  asm volatile("s_waitcnt lgkmcnt(0)" ::: "memory");
  __builtin_amdgcn_s_barrier();
  STG64(2, SBUF(0));                                   // qU tile region now dead

  float rmx[4][4];
  #pragma unroll
  for (int i = 0; i < 4; ++i)
    #pragma unroll
    for (int r = 0; r < 4; ++r) rmx[i][r] = -3.4e38f;

  // direct-AGPR MFMA: D/C = "+v" acc, SrcA = "a" fragment, SrcB = "v".
  // Non-volatile: pure computation, ordered by data deps only.
#define MFA(I, KQ, BV, C)                                                      \
    asm("v_mfma_f32_16x16x32_bf16 %0, %1, %2, %0"                              \
        : "+v"(C) : "a"(aqf[I][KQ]), "v"(BV))

  // per tile: 8 ds_read_b128 (B only; A from AGPRs, zero transport), 32 MFMA.
#define CMP64(tb, buf) do {                                                    \
    f4v c0 = {}, c1 = {}, c2 = {}, c3 = {};                                    \
    const unsigned short* bp_ = &(buf)[(wc16 + m16) * 256];                    \
    const s8v bv0 = *(const s8v*)&bp_[((0 * 4 + quad) ^ (m16 & 7)) * 8];       \
    const s8v bv1 = *(const s8v*)&bp_[((1 * 4 + quad) ^ (m16 & 7)) * 8];       \
    const s8v bv2 = *(const s8v*)&bp_[((2 * 4 + quad) ^ (m16 & 7)) * 8];       \
    const s8v bv3 = *(const s8v*)&bp_[((3 * 4 + quad) ^ (m16 & 7)) * 8];       \
    const s8v bv4 = *(const s8v*)&bp_[((4 * 4 + quad) ^ (m16 & 7)) * 8];       \
    const s8v bv5 = *(const s8v*)&bp_[((5 * 4 + quad) ^ (m16 & 7)) * 8];       \
    const s8v bv6 = *(const s8v*)&bp_[((6 * 4 + quad) ^ (m16 & 7)) * 8];       \
    const s8v bv7 = *(const s8v*)&bp_[((7 * 4 + quad) ^ (m16 & 7)) * 8];       \
    MFA(0, 0, bv0, c0); MFA(1, 0, bv0, c1); MFA(2, 0, bv0, c2); MFA(3, 0, bv0, c3); \
    MFA(0, 1, bv1, c0); MFA(1, 1, bv1, c1); MFA(2, 1, bv1, c2); MFA(3, 1, bv1, c3); \
    MFA(0, 2, bv2, c0); MFA(1, 2, bv2, c1); MFA(2, 2, bv2, c2); MFA(3, 2, bv2, c3); \
    MFA(0, 3, bv3, c0); MFA(1, 3, bv3, c1); MFA(2, 3, bv3, c2); MFA(3, 3, bv3, c3); \
    MFA(0, 4, bv4, c0); MFA(1, 4, bv4, c1); MFA(2, 4, bv4, c2); MFA(3, 4, bv4, c3); \
    MFA(0, 5, bv5, c0); MFA(1, 5, bv5, c1); MFA(2, 5, bv5, c2); MFA(3, 5, bv5, c3); \
    MFA(0, 6, bv6, c0); MFA(1, 6, bv6, c1); MFA(2, 6, bv6, c2); MFA(3, 6, bv6, c3); \
    MFA(0, 7, bv7, c0); MFA(1, 7, bv7, c1); MFA(2, 7, bv7, c2); MFA(3, 7, bv7, c3); \
    /* asm MFMA is opaque to the hazard recognizer: cover MFMA-write(c) ->  */  \
    /* VALU-read with 16 cycles; c0 (written 4 MFMAs back) is read first.  */   \
    asm volatile("s_nop 7\n\ts_nop 7" :::);                                    \
    _Pragma("unroll")                                                          \
    for (int r_ = 0; r_ < 4; ++r_) {                                           \
      rmx[0][r_] = fmaxf(rmx[0][r_], c0[r_]);                                  \
      rmx[1][r_] = fmaxf(rmx[1][r_], c1[r_]);                                  \
      rmx[2][r_] = fmaxf(rmx[2][r_], c2[r_]);                                  \
      rmx[3][r_] = fmaxf(rmx[3][r_], c3[r_]);                                  \
    }                                                                          \
    float v_ = fmaxf(fmaxf(fmaxf(c0[0], c0[1]), fmaxf(c0[2], c0[3])),          \
                     fmaxf(fmaxf(c1[0], c1[1]), fmaxf(c1[2], c1[3])));         \
    v_ = fmaxf(v_, fmaxf(fmaxf(fmaxf(c2[0], c2[1]), fmaxf(c2[2], c2[3])),      \
                         fmaxf(fmaxf(c3[0], c3[1]), fmaxf(c3[2], c3[3]))));    \
    v_ = fmaxf(v_, __shfl_xor(v_, 16));                                        \
    v_ = fmaxf(v_, __shfl_xor(v_, 32));                                        \
    if (quad == 0) atomicMax(&colLds[(tb) * 64 + wc16 + m16], encf(v_));       \
  } while (0)

  // depth-3 ring pipeline: before compute(t), tiles t+1..t+3 staged (12 in
  // flight) -> vmcnt(8) proves tile t landed. stage(t+3) targets SBUF((t+1)&3)
  // = the buffer freed by compute(t-1); two barriers separate them.
  #pragma unroll 1
  for (int t = 0; t < 30; ++t) {
    asm volatile("s_waitcnt vmcnt(8)" ::: "memory");   // tile t's 4/thread landed
    __builtin_amdgcn_s_barrier();                      // ...for ALL waves
    if (t <= 28) STG64(t + 3, SBUF((t + 1) & 3));
    CMP64(t, SBUF((t + 2) & 3));
    __builtin_amdgcn_s_barrier();                      // buf reads done -> restage-safe
  }
  asm volatile("s_waitcnt vmcnt(4)" ::: "memory");     // tile 30 landed
  __builtin_amdgcn_s_barrier();
  CMP64(30, SBUF(0));
  __builtin_amdgcn_s_barrier();
  asm volatile("s_waitcnt vmcnt(0)" ::: "memory");     // tile 31 landed
  __builtin_amdgcn_s_barrier();
  CMP64(31, SBUF(1));

  // ---- final row maxes: shuffle over m16, combine via LDS, store ----
  #pragma unroll
  for (int i = 0; i < 4; ++i)
    #pragma unroll
    for (int r = 0; r < 4; ++r) {
      float v = rmx[i][r];
      #pragma unroll
      for (int d2 = 1; d2 < 16; d2 <<= 1) v = fmaxf(v, __shfl_xor(v, d2));
      if (m16 == 0) atomicMax(&rowLds[wm * 64 + i * 16 + quad * 4 + r], encf(v));
    }
  __syncthreads();
  if (tid < 128)
    rowmax[(long)b * 2048 + tm * 128 + tid] = rowLds[tid];   // plain store (block owns rows)
  // ---- col maxes: one global atomic pass ----
  #pragma unroll
  for (int i = 0; i < 4; ++i)
    atomicMax(&colmax[(long)b * 2048 + i * 512 + tid], colLds[i * 512 + tid]);
}

// ---------- fused softmax + weighted sum (bf16 inputs, 16B/lane loads) ----------
__global__ void wsum_kernel(const uint4* __restrict__ qb, const uint4* __restrict__ ab,
                            const unsigned* __restrict__ rowmax, const unsigned* __restrict__ colmax,
                            float* __restrict__ out) {
  const int tid = threadIdx.x;
  const int chunk = blockIdx.x;
  const int b = blockIdx.y;
  const int z = blockIdx.z;
  const unsigned* e = z ? colmax : rowmax;
  const uint4* src = z ? ab : qb;

  __shared__ float sm[4];
  __shared__ float ss[4];
  __shared__ float wLds[128];
  __shared__ float red[256 * 8];   // 8 KB

  float x[8];
  float m = -3.4e38f;
  #pragma unroll
  for (int j = 0; j < 8; ++j) {
    x[j] = tanhf(decf(e[b * 2048 + j * 256 + tid]));
    m = fmaxf(m, x[j]);
  }
  #pragma unroll
  for (int d2 = 1; d2 < 64; d2 <<= 1) m = fmaxf(m, __shfl_xor(m, d2));
  if ((tid & 63) == 0) sm[tid >> 6] = m;
  __syncthreads();
  m = fmaxf(fmaxf(sm[0], sm[1]), fmaxf(sm[2], sm[3]));
  float s = 0.f;
  #pragma unroll
  for (int j = 0; j < 8; ++j) s += expf(x[j] - m);
  #pragma unroll
  for (int d2 = 1; d2 < 64; d2 <<= 1) s += __shfl_xor(s, d2);
  if ((tid & 63) == 0) ss[tid >> 6] = s;
  __syncthreads();
  const float inv = 1.f / (ss[0] + ss[1] + ss[2] + ss[3]);

  if (tid < 128) {
    float xv = tanhf(decf(e[b * 2048 + chunk * 128 + tid]));
    wLds[tid] = expf(xv - m) * inv;
  }
  __syncthreads();

  const int dg = tid & 31;
  const int rg = tid >> 5;       // 0..7, rows stride 8
  float acc[8] = {};
  const long rowbase = (long)b * 2048 + chunk * 128;
  for (int t = rg; t < 128; t += 8) {
    const float wgt = wLds[t];
    uint4 v = src[(rowbase + t) * 32 + dg];
    acc[0] += wgt * __uint_as_float(v.x << 16);
    acc[1] += wgt * __uint_as_float(v.x & 0xFFFF0000u);
    acc[2] += wgt * __uint_as_float(v.y << 16);
    acc[3] += wgt * __uint_as_float(v.y & 0xFFFF0000u);
    acc[4] += wgt * __uint_as_float(v.z << 16);
    acc[5] += wgt * __uint_as_float(v.z & 0xFFFF0000u);
    acc[6] += wgt * __uint_as_float(v.w << 16);
    acc[7] += wgt * __uint_as_float(v.w & 0xFFFF0000u);
  }
  #pragma unroll
  for (int k = 0; k < 8; ++k) red[tid * 8 + k] = acc[k];
  __syncthreads();
  if (tid < 32) {
    #pragma unroll
    for (int k = 0; k < 8; ++k) {
      float v = 0.f;
      #pragma unroll
      for (int g = 0; g < 8; ++g) v += red[((g << 5) | tid) * 8 + k];
      atomicAdd(&out[z * 4096 + b * 256 + tid * 8 + k], v);
    }
  }
}

// ---------- launch ----------
extern "C" void kernel_launch(void* const* d_in, const int* in_sizes, int n_in,
                              void* d_out, int out_size, void* d_ws, size_t ws_size,
                              hipStream_t stream) {
  const float* q = (const float*)d_in[0];
  const float* a = (const float*)d_in[1];
  const float* U = (const float*)d_in[2];
  float* out = (float*)d_out;

  char* w = (char*)d_ws;
  unsigned short* qb = (unsigned short*)w;                       // 16 MB
  unsigned short* ab = (unsigned short*)(w + (16ull << 20));     // 16 MB
  unsigned short* Ut = (unsigned short*)(w + (32ull << 20));     // 128 KB
  unsigned* rmax = (unsigned*)(w + (32ull << 20) + (128ull << 10));
  unsigned* cmax = rmax + 32768;

  // allow 139776 B dynamic LDS for the fused kernel (host-side, idempotent)
  constexpr int SMEM = 139776;
  hipFuncSetAttribute((const void*)fused_qu_smax,
                      hipFuncAttributeMaxDynamicSharedMemorySize, SMEM);

  // fused q/a bf16-cast + U transpose + rmax/cmax zero + out zero
  convert_kernel<<<8352, 256, 0, stream>>>((const float4*)q, (const float4*)a, U,
                                           (ushort4*)qb, (ushort4*)ab, Ut, rmax, out);

  // qU tile in LDS + S row/col maxes; grid (b, tm) -> XCD == b%8; 8 waves/block
  fused_qu_smax<<<dim3(16, 16), 512, SMEM, stream>>>(qb, Ut, ab, rmax, cmax);

  // fused softmax + weighted pooling (bf16, 16B/lane)
  wsum_kernel<<<dim3(16, 16, 2), 256, 0, stream>>>((const uint4*)qb, (const uint4*)ab,
                                                   rmax, cmax, out);
}